// Round 5
// baseline (22863.974 us; speedup 1.0000x reference)
//
#include <hip/hip_runtime.h>
#include <stdint.h>

#define NN 100000
#define NE 1600000
#define KG 15
#define CHUNK 2500
#define NCHUNKS 40

typedef unsigned short u16;

static __device__ __forceinline__ float bf2f(u16 u){ return __uint_as_float(((unsigned)u)<<16); }
static __device__ __forceinline__ u16 f2bf(float f){
  unsigned u = __float_as_uint(f);
  u += 0x7FFFu + ((u>>16)&1u);       // RNE
  return (u16)(u>>16);
}
static __device__ __forceinline__ float ldf(const void* p, long long i, int isf32){
  return isf32 ? ((const float*)p)[i] : bf2f(((const u16*)p)[i]);
}
static __device__ __forceinline__ int ld_idx(const void* p, long long i, int isi64){
  return isi64 ? (int)((const long long*)p)[i] : ((const int*)p)[i];
}

// ---------------- sentinel (f32 output) ----------------
__global__ void k_sentinel(float* out, float val){
  if (threadIdx.x == 0 && blockIdx.x == 0) out[0] = val;
}

// ---------------- dtype probe ----------------
__global__ void k_probe(const void* sg1, const void* ei, int* flags){
  if (threadIdx.x == 0 && blockIdx.x == 0){
    const u16* p = (const u16*)sg1;        // sigma1: 45 values in [1.0, 1.1]
    int sane = 1;
    for (int i=0;i<45;i++){ float v = bf2f(p[i]); if (!(v > 0.5f && v < 2.0f)) sane = 0; }
    flags[0] = sane ? 0 : 1;               // isf32
    const int* q = (const int*)ei;         // int64 => odd words all zero
    int allz = 1;
    for (int i=1;i<128;i+=2) if (q[i] != 0) allz = 0;
    flags[1] = allz ? 1 : 0;               // isi64
  }
}

// ---------------- CSR build (perm only) ----------------
__global__ __launch_bounds__(256) void k_deg(const void* ei, int* __restrict__ deg, const int* flags){
  int e = blockIdx.x*256 + threadIdx.x;           // grid exact: NE/256
  int isi64 = flags[1];
  atomicAdd(&deg[ld_idx(ei, (long long)NE + e, isi64)], 1);
}

__global__ __launch_bounds__(256) void k_scan1(const int* __restrict__ deg, int* __restrict__ rp,
                                               int* __restrict__ bsum){
  __shared__ int lds[256];
  int b = blockIdx.x, t = threadIdx.x;
  int base = b*1024 + t*4;
  int v[4]; int s = 0;
  #pragma unroll
  for (int i=0;i<4;i++){ v[i] = (base+i < NN) ? deg[base+i] : 0; s += v[i]; }
  lds[t] = s; __syncthreads();
  int inc = s;
  for (int off=1; off<256; off<<=1){
    int y = (t>=off) ? lds[t-off] : 0;
    __syncthreads();
    inc += y; lds[t] = inc;
    __syncthreads();
  }
  int excl = inc - s;
  #pragma unroll
  for (int i=0;i<4;i++){ if (base+i < NN) rp[base+i] = excl; excl += v[i]; }
  if (t == 255) bsum[b] = inc;
}

__global__ __launch_bounds__(128) void k_scan2(int* __restrict__ bsum, int* __restrict__ rp){
  __shared__ int lds[128];
  int t = threadIdx.x;
  const int nb = (NN + 1023)/1024;   // 98
  int s = (t < nb) ? bsum[t] : 0;
  lds[t] = s; __syncthreads();
  int inc = s;
  for (int off=1; off<128; off<<=1){
    int y = (t>=off) ? lds[t-off] : 0;
    __syncthreads();
    inc += y; lds[t] = inc;
    __syncthreads();
  }
  bsum[t] = inc - s;                 // exclusive block offsets
  if (t == 0) rp[NN] = NE;
}

__global__ __launch_bounds__(256) void k_scan3(int* __restrict__ rp, const int* __restrict__ bsum){
  int b = blockIdx.x, t = threadIdx.x;
  int add = bsum[b];
  int base = b*1024 + t*4;
  #pragma unroll
  for (int i=0;i<4;i++) if (base+i < NN) rp[base+i] += add;
}

__global__ __launch_bounds__(256) void k_fillp(const void* ei, const int* __restrict__ rp,
                                               int* __restrict__ cur, int* __restrict__ perm,
                                               const int* flags){
  int e = blockIdx.x*256 + threadIdx.x;           // grid exact
  int isi64 = flags[1];
  int t = ld_idx(ei, (long long)NE + e, isi64);
  int p = rp[t] + atomicAdd(&cur[t], 1);
  perm[p] = e;
}

// ---------------- Phase A (VALU): per-node edge aggregation ----------------
template<int CIN>
__global__ __launch_bounds__(256) void k_phaseAv(
    const int* __restrict__ perm, const int* __restrict__ rp,
    const void* ei, const void* attr,
    const void* xin, int xmode, const void* mu, const void* sg,
    u16* __restrict__ ab, int c0, const int* flags)
{
  constexpr int KC   = CIN*KG;
  constexpr int KPAD = ((KC + CIN + 31)/32)*32;
  constexpr int P    = (CIN + 63)/64;
  int isf = flags[0], isi64 = flags[1];
  int xisf = xmode ? isf : 0;
  int wv = threadIdx.x >> 6, l = threadIdx.x & 63;
  int t = c0 + blockIdx.x*4 + wv;
  int rs = rp[t], re = rp[t+1];
  int kk = (l < KG) ? l : 0;
  float mu0 = ldf(mu, kk*3+0, isf), mu1 = ldf(mu, kk*3+1, isf), mu2 = ldf(mu, kk*3+2, isf);
  float s0 = ldf(sg, kk*3+0, isf),  s1 = ldf(sg, kk*3+1, isf),  s2 = ldf(sg, kk*3+2, isf);
  float is0 = 1.f/(s0*s0 + 1e-15f), is1 = 1.f/(s1*s1 + 1e-15f), is2 = 1.f/(s2*s2 + 1e-15f);

  float z[KG][P];
  #pragma unroll
  for (int k=0;k<KG;k++)
    #pragma unroll
    for (int p=0;p<P;p++) z[k][p] = 0.f;

  for (int e = rs; e < re; e++){
    int eidx = perm[e];
    float u0 = ldf(attr, 3LL*eidx+0, isf);
    float u1 = ldf(attr, 3LL*eidx+1, isf);
    float u2 = ldf(attr, 3LL*eidx+2, isf);
    int srcn = ld_idx(ei, eidx, isi64);
    float w = 0.f;
    if (l < KG){
      float d0 = u0 - mu0, d1 = u1 - mu1, d2 = u2 - mu2;
      w = __expf(-0.5f*(d0*d0*is0 + d1*d1*is1 + d2*d2*is2));
    }
    float xv[P];
    #pragma unroll
    for (int p=0;p<P;p++){
      int cin = l + 64*p;
      xv[p] = (cin < CIN) ? ldf(xin, (long long)srcn*CIN + cin, xisf) : 0.f;
    }
    #pragma unroll
    for (int k=0;k<KG;k++){
      float wk = __shfl(w, k, 64);
      #pragma unroll
      for (int p=0;p<P;p++) z[k][p] += wk*xv[p];
    }
  }

  int dg = re - rs;
  float inv = 1.f / (float)(dg > 0 ? dg : 1);
  u16* row = ab + (size_t)(t - c0)*KPAD;
  #pragma unroll
  for (int p=0;p<P;p++){
    int cin = l + 64*p;
    if (cin < CIN){
      #pragma unroll
      for (int k=0;k<KG;k++) row[cin*KG + k] = f2bf(z[k][p]*inv);
    }
  }
  for (int idx = l; idx < KPAD - KC; idx += 64){
    u16 v = 0;
    if (idx < CIN) v = f2bf(ldf(xin, (long long)t*CIN + idx, xisf));
    row[KC + idx] = v;
  }
}

// ---------------- plain f32 weight repack: bpf[kk][c] (COUTP=128) ----------------
__global__ __launch_bounds__(256) void k_repackf(const void* g, const void* root, float* __restrict__ bpf,
                                                 int KC, int CIN, int COUT, int KPAD, const int* flags){
  int tid = blockIdx.x*256 + threadIdx.x;
  int total = KPAD*128;
  if (tid >= total) return;
  int isf = flags[0];
  int kk = tid >> 7, c = tid & 127;
  float v = 0.f;
  if (c < COUT){
    if (kk < KC)            v = ldf(g, (long long)kk*COUT + c, isf);
    else if (kk < KC + CIN) v = ldf(root, (long long)(kk-KC)*COUT + c, isf);
  }
  bpf[tid] = v;
}

// ---------------- Phase B (VALU): [CHUNK,KPAD] @ [KPAD,COUT] + bias (+ELU) ----------------
template<int KPAD, bool FINAL>
__global__ __launch_bounds__(256) void k_phaseBv(
    const u16* __restrict__ ab, const float* __restrict__ bpf, const void* bias,
    u16* __restrict__ h, float* __restrict__ outp, int c0, int COUT, const int* flags)
{
  int tpos = threadIdx.x;
  int c = tpos & 127, ng = tpos >> 7;
  int n4 = (blockIdx.x*2 + ng)*4;
  if (n4 >= CHUNK || c >= COUT) return;
  int isf = flags[0];
  const u16* ar = ab + (size_t)n4*KPAD;
  float acc0=0.f, acc1=0.f, acc2=0.f, acc3=0.f;
  for (int kk=0; kk<KPAD; kk++){
    float bv = bpf[kk*128 + c];
    float a0 = bf2f(ar[kk]);
    float a1 = bf2f(ar[KPAD + kk]);
    float a2 = bf2f(ar[2*KPAD + kk]);
    float a3 = bf2f(ar[3*KPAD + kk]);
    acc0 += a0*bv; acc1 += a1*bv; acc2 += a2*bv; acc3 += a3*bv;
  }
  float bb = ldf(bias, c, isf);
  float v[4] = {acc0+bb, acc1+bb, acc2+bb, acc3+bb};
  #pragma unroll
  for (int i=0;i<4;i++){
    int node = c0 + n4 + i;
    float x = v[i];
    if (!FINAL){
      x = (x > 0.f) ? x : (__expf(x) - 1.f);   // ELU
      h[(size_t)node*COUT + c] = f2bf(x);
    } else {
      outp[(size_t)node*COUT + c] = x;          // f32 output
    }
  }
}

// ---------------- BN stats + apply ----------------
__global__ __launch_bounds__(256) void k_stats(const u16* __restrict__ h, float* __restrict__ sums,
                                               float* __restrict__ sumsq, int COUT){
  __shared__ float sS[256], sQ[256];
  int t = threadIdx.x;
  int c = t & 127, rg = t >> 7;
  float s = 0.f, qq = 0.f;
  int r0 = blockIdx.x*512 + rg*256;
  if (c < COUT){
    for (int i=0;i<256;i++){
      int r = r0 + i;
      if (r < NN){ float v = bf2f(h[(size_t)r*COUT + c]); s += v; qq += v*v; }
    }
  }
  sS[t] = s; sQ[t] = qq; __syncthreads();
  if (t < 128){
    float a = sS[t] + sS[t+128];
    float b = sQ[t] + sQ[t+128];
    if (t < COUT){ atomicAdd(&sums[t], a); atomicAdd(&sumsq[t], b); }
  }
}

__global__ __launch_bounds__(256) void k_bn(const u16* __restrict__ h, const void* gamma,
                                            const void* beta, const float* __restrict__ sums,
                                            const float* __restrict__ sumsq, u16* __restrict__ xo,
                                            int COUT, const int* flags){
  int t = threadIdx.x;
  int isf = flags[0];
  int c = t & 127;
  int r = blockIdx.x*2 + (t >> 7);
  if (c >= COUT || r >= NN) return;
  const float invn = 1.f/(float)NN;
  float mean = sums[c]*invn;
  float var  = sumsq[c]*invn - mean*mean;
  float g = ldf(gamma, c, isf), b = ldf(beta, c, isf);
  float v = g*(bf2f(h[(size_t)r*COUT + c]) - mean)*rsqrtf(var + 1e-5f) + b;
  xo[(size_t)r*COUT + c] = f2bf(v);
}

// ---------------- host ----------------
extern "C" void kernel_launch(void* const* d_in, const int* in_sizes, int n_in,
                              void* d_out, int out_size, void* d_ws, size_t ws_size,
                              hipStream_t stream)
{
  // ---- input mapping self-check ----
  static const int expected[29] = {
    5000000, 3200000, 4800000,
    56250, 45, 45, 3750, 75, 75, 75,
    112500, 45, 45, 7500, 100, 100, 100,
    112500, 45, 45, 7500, 75, 75, 75,
    56250, 45, 45, 3750, 50
  };
  if (n_in != 29){
    k_sentinel<<<1, 64, 0, stream>>>((float*)d_out, 512.0f);
    return;
  }
  for (int j=0;j<29;j++){
    if (in_sizes[j] != expected[j]){
      k_sentinel<<<1, 64, 0, stream>>>((float*)d_out, 1024.0f*(float)(1+j));
      return;
    }
  }

  const void* x0   = d_in[0];
  const void* ei   = d_in[1];
  const void* attr = d_in[2];
  const void* G[4]  = {d_in[3],  d_in[10], d_in[17], d_in[24]};
  const void* MU[4] = {d_in[4],  d_in[11], d_in[18], d_in[25]};
  const void* SG[4] = {d_in[5],  d_in[12], d_in[19], d_in[26]};
  const void* RT[4] = {d_in[6],  d_in[13], d_in[20], d_in[27]};
  const void* BI[4] = {d_in[7],  d_in[14], d_in[21], d_in[28]};
  const void* GA[3] = {d_in[8],  d_in[15], d_in[22]};
  const void* BE[3] = {d_in[9],  d_in[16], d_in[23]};

  char* w = (char*)d_ws;
  auto alloc = [&](size_t bytes)->char*{ char* p = w; w += (bytes + 255) & ~(size_t)255; return p; };
  int*  flags = (int*) alloc(256);
  int*  deg  = (int*) alloc((size_t)NN*4);
  int*  cur  = (int*) alloc((size_t)NN*4);
  int*  rp   = (int*) alloc((size_t)(NN+1)*4);
  int*  bsum = (int*) alloc(512*4);
  int*  perm = (int*) alloc((size_t)NE*4);             // 6.4 MB
  u16*  ab   = (u16*) alloc((size_t)CHUNK*1600*2);     // 8 MB
  u16*  h    = (u16*) alloc((size_t)NN*100*2);         // 20 MB
  u16*  xb   = (u16*) alloc((size_t)NN*100*2);         // 20 MB
  float* bpf = (float*)alloc((size_t)1600*128*4);      // 0.82 MB
  float* sums  = (float*)alloc(512);
  float* sumsq = (float*)alloc(512);

  size_t needed = (size_t)(w - (char*)d_ws);
  if (ws_size < needed){
    float mb = (float)(ws_size >> 20); if (mb > 255.f) mb = 255.f;
    k_sentinel<<<1, 64, 0, stream>>>((float*)d_out, 65536.0f + 256.0f*mb);
    return;
  }

  k_probe<<<1, 64, 0, stream>>>(SG[0], ei, flags);

  hipMemsetAsync(deg, 0, (size_t)NN*4, stream);
  hipMemsetAsync(cur, 0, (size_t)NN*4, stream);
  k_deg  <<<NE/256, 256, 0, stream>>>(ei, deg, flags);
  k_scan1<<<(NN+1023)/1024, 256, 0, stream>>>(deg, rp, bsum);
  k_scan2<<<1, 128, 0, stream>>>(bsum, rp);
  k_scan3<<<(NN+1023)/1024, 256, 0, stream>>>(rp, bsum);
  k_fillp<<<NE/256, 256, 0, stream>>>(ei, rp, cur, perm, flags);

  const int pbGrid = (CHUNK + 7)/8;   // 313

  // ---- layer 1: 50 -> 75
  k_repackf<<<(800*128 + 255)/256, 256, 0, stream>>>(G[0], RT[0], bpf, 750, 50, 75, 800, flags);
  hipMemsetAsync(sums, 0, 512, stream); hipMemsetAsync(sumsq, 0, 512, stream);
  for (int c=0; c<NCHUNKS; c++){
    k_phaseAv<50><<<CHUNK/4, 256, 0, stream>>>(perm, rp, ei, attr, x0, 1, MU[0], SG[0], ab, c*CHUNK, flags);
    k_phaseBv<800,false><<<pbGrid, 256, 0, stream>>>(ab, bpf, BI[0], h, nullptr, c*CHUNK, 75, flags);
  }
  k_stats<<<(NN+511)/512, 256, 0, stream>>>(h, sums, sumsq, 75);
  k_bn<<<NN/2, 256, 0, stream>>>(h, GA[0], BE[0], sums, sumsq, xb, 75, flags);

  // ---- layer 2: 75 -> 100
  k_repackf<<<(1216*128 + 255)/256, 256, 0, stream>>>(G[1], RT[1], bpf, 1125, 75, 100, 1216, flags);
  hipMemsetAsync(sums, 0, 512, stream); hipMemsetAsync(sumsq, 0, 512, stream);
  for (int c=0; c<NCHUNKS; c++){
    k_phaseAv<75><<<CHUNK/4, 256, 0, stream>>>(perm, rp, ei, attr, xb, 0, MU[1], SG[1], ab, c*CHUNK, flags);
    k_phaseBv<1216,false><<<pbGrid, 256, 0, stream>>>(ab, bpf, BI[1], h, nullptr, c*CHUNK, 100, flags);
  }
  k_stats<<<(NN+511)/512, 256, 0, stream>>>(h, sums, sumsq, 100);
  k_bn<<<NN/2, 256, 0, stream>>>(h, GA[1], BE[1], sums, sumsq, xb, 100, flags);

  // ---- layer 3: 100 -> 75
  k_repackf<<<(1600*128 + 255)/256, 256, 0, stream>>>(G[2], RT[2], bpf, 1500, 100, 75, 1600, flags);
  hipMemsetAsync(sums, 0, 512, stream); hipMemsetAsync(sumsq, 0, 512, stream);
  for (int c=0; c<NCHUNKS; c++){
    k_phaseAv<100><<<CHUNK/4, 256, 0, stream>>>(perm, rp, ei, attr, xb, 0, MU[2], SG[2], ab, c*CHUNK, flags);
    k_phaseBv<1600,false><<<pbGrid, 256, 0, stream>>>(ab, bpf, BI[2], h, nullptr, c*CHUNK, 75, flags);
  }
  k_stats<<<(NN+511)/512, 256, 0, stream>>>(h, sums, sumsq, 75);
  k_bn<<<NN/2, 256, 0, stream>>>(h, GA[2], BE[2], sums, sumsq, xb, 75, flags);

  // ---- layer 4: 75 -> 50 (no ELU, no BN, f32 out)
  k_repackf<<<(1216*128 + 255)/256, 256, 0, stream>>>(G[3], RT[3], bpf, 1125, 75, 50, 1216, flags);
  for (int c=0; c<NCHUNKS; c++){
    k_phaseAv<75><<<CHUNK/4, 256, 0, stream>>>(perm, rp, ei, attr, xb, 0, MU[3], SG[3], ab, c*CHUNK, flags);
    k_phaseBv<1216,true><<<pbGrid, 256, 0, stream>>>(ab, bpf, BI[3], nullptr, (float*)d_out, c*CHUNK, 50, flags);
  }
}

// Round 6
// 3041.043 us; speedup vs baseline: 7.5185x; 7.5185x over previous
//
#include <hip/hip_runtime.h>
#include <stdint.h>

#define NN 100000
#define NE 1600000
#define KG 15

typedef unsigned short u16;
typedef __attribute__((ext_vector_type(8))) short short8;
typedef __attribute__((ext_vector_type(8))) __bf16 bf16x8;
typedef __attribute__((ext_vector_type(4))) float f32x4;

static __device__ __forceinline__ float bf2f(u16 u){ return __uint_as_float(((unsigned)u)<<16); }
static __device__ __forceinline__ u16 f2bf(float f){
  unsigned u = __float_as_uint(f);
  u += 0x7FFFu + ((u>>16)&1u);       // RNE
  return (u16)(u>>16);
}
static __device__ __forceinline__ float ldf(const void* p, long long i, int isf32){
  return isf32 ? ((const float*)p)[i] : bf2f(((const u16*)p)[i]);
}
static __device__ __forceinline__ int ld_idx(const void* p, long long i, int isi64){
  return isi64 ? (int)((const long long*)p)[i] : ((const int*)p)[i];
}
static __device__ __forceinline__ f32x4 mfma16x16x32(short8 a, short8 b, f32x4 c){
  return __builtin_amdgcn_mfma_f32_16x16x32_bf16(
      __builtin_bit_cast(bf16x8, a), __builtin_bit_cast(bf16x8, b), c, 0, 0, 0);
}

// ---------------- sentinel (f32 output) ----------------
__global__ void k_sentinel(float* out, float val){
  if (threadIdx.x == 0 && blockIdx.x == 0) out[0] = val;
}

// ---------------- dtype probe ----------------
__global__ void k_probe(const void* sg1, const void* ei, int* flags){
  if (threadIdx.x == 0 && blockIdx.x == 0){
    const u16* p = (const u16*)sg1;        // sigma1: 45 values in [1.0, 1.1]
    int sane = 1;
    for (int i=0;i<45;i++){ float v = bf2f(p[i]); if (!(v > 0.5f && v < 2.0f)) sane = 0; }
    flags[0] = sane ? 0 : 1;               // isf32
    const int* q = (const int*)ei;         // int64 => odd words all zero
    int allz = 1;
    for (int i=1;i<128;i+=2) if (q[i] != 0) allz = 0;
    flags[1] = allz ? 1 : 0;               // isi64
  }
}

// ---------------- CSR build (perm only) ----------------
__global__ __launch_bounds__(256) void k_deg(const void* ei, int* __restrict__ deg, const int* flags){
  int e = blockIdx.x*256 + threadIdx.x;           // grid exact: NE/256
  int isi64 = flags[1];
  atomicAdd(&deg[ld_idx(ei, (long long)NE + e, isi64)], 1);
}

__global__ __launch_bounds__(256) void k_scan1(const int* __restrict__ deg, int* __restrict__ rp,
                                               int* __restrict__ bsum){
  __shared__ int lds[256];
  int b = blockIdx.x, t = threadIdx.x;
  int base = b*1024 + t*4;
  int v[4]; int s = 0;
  #pragma unroll
  for (int i=0;i<4;i++){ v[i] = (base+i < NN) ? deg[base+i] : 0; s += v[i]; }
  lds[t] = s; __syncthreads();
  int inc = s;
  for (int off=1; off<256; off<<=1){
    int y = (t>=off) ? lds[t-off] : 0;
    __syncthreads();
    inc += y; lds[t] = inc;
    __syncthreads();
  }
  int excl = inc - s;
  #pragma unroll
  for (int i=0;i<4;i++){ if (base+i < NN) rp[base+i] = excl; excl += v[i]; }
  if (t == 255) bsum[b] = inc;
}

__global__ __launch_bounds__(128) void k_scan2(int* __restrict__ bsum, int* __restrict__ rp){
  __shared__ int lds[128];
  int t = threadIdx.x;
  const int nb = (NN + 1023)/1024;   // 98
  int s = (t < nb) ? bsum[t] : 0;
  lds[t] = s; __syncthreads();
  int inc = s;
  for (int off=1; off<128; off<<=1){
    int y = (t>=off) ? lds[t-off] : 0;
    __syncthreads();
    inc += y; lds[t] = inc;
    __syncthreads();
  }
  bsum[t] = inc - s;                 // exclusive block offsets
  if (t == 0) rp[NN] = NE;
}

__global__ __launch_bounds__(256) void k_scan3(int* __restrict__ rp, const int* __restrict__ bsum){
  int b = blockIdx.x, t = threadIdx.x;
  int add = bsum[b];
  int base = b*1024 + t*4;
  #pragma unroll
  for (int i=0;i<4;i++) if (base+i < NN) rp[base+i] += add;
}

__global__ __launch_bounds__(256) void k_fillp(const void* ei, const int* __restrict__ rp,
                                               int* __restrict__ cur, int* __restrict__ perm,
                                               const int* flags){
  int e = blockIdx.x*256 + threadIdx.x;           // grid exact
  int isi64 = flags[1];
  int t = ld_idx(ei, (long long)NE + e, isi64);
  int p = rp[t] + atomicAdd(&cur[t], 1);
  perm[p] = e;
}

// ---------------- Phase A (MFMA): per-node edge aggregation ----------------
// wave per node. A-frag: A[m=lane&15 = gaussian][k=q*8+j = edge slot].
// B-frag: B[k=q*8+j = edge slot][n=lane&15 (+16ct) = cin]. D: row=q*4+reg = gaussian,
// col=lane&15 = cin. Gaussian row 15 is zero pad. (Layout validated: rounds 2 vs 3/4
// produced bit-identical outputs.)
template<int CIN>
__global__ __launch_bounds__(256) void k_phaseA(
    const int* __restrict__ perm, const int* __restrict__ rp,
    const void* ei, const void* attr,
    const void* xin, int xmode, const void* mu, const void* sg,
    u16* __restrict__ ab, int c0, int nrows, const int* flags)
{
  constexpr int KC   = CIN*KG;
  constexpr int KPAD = ((KC + CIN + 31)/32)*32;
  constexpr int NT   = (CIN + 15)/16;
  int isf = flags[0], isi64 = flags[1];
  int xisf = xmode ? isf : 0;
  int wv = threadIdx.x >> 6, lane = threadIdx.x & 63;
  int t = c0 + blockIdx.x*4 + wv;
  if (t >= c0 + nrows) return;
  int m = lane & 15, q = lane >> 4;
  int rs = rp[t], re = rp[t+1];
  bool kvalid = (m < KG);
  int mm = kvalid ? m : 0;
  float mu0 = ldf(mu, mm*3+0, isf), mu1 = ldf(mu, mm*3+1, isf), mu2 = ldf(mu, mm*3+2, isf);
  float s0 = ldf(sg, mm*3+0, isf),  s1 = ldf(sg, mm*3+1, isf),  s2 = ldf(sg, mm*3+2, isf);
  float is0 = 1.f/(s0*s0 + 1e-15f), is1 = 1.f/(s1*s1 + 1e-15f), is2 = 1.f/(s2*s2 + 1e-15f);

  f32x4 acc[NT] = {};
  for (int base = rs; base < re; base += 32){
    int e0 = base + q*8;
    short8 af;
    int srcs[8];
    #pragma unroll
    for (int j=0;j<8;j++){
      int ep = e0 + j;
      float w = 0.f; int srcj = 0;
      if (ep < re){
        int eidx = perm[ep];
        srcj = ld_idx(ei, eidx, isi64);
        if (kvalid){
          float d0 = ldf(attr, 3LL*eidx+0, isf) - mu0;
          float d1 = ldf(attr, 3LL*eidx+1, isf) - mu1;
          float d2 = ldf(attr, 3LL*eidx+2, isf) - mu2;
          w = __expf(-0.5f*(d0*d0*is0 + d1*d1*is1 + d2*d2*is2));
        }
      }
      srcs[j] = srcj;
      af[j] = (short)f2bf(w);
    }
    #pragma unroll
    for (int ct=0; ct<NT; ct++){
      int cin = ct*16 + m;
      short8 bf = {};
      if (cin < CIN){
        #pragma unroll
        for (int j=0;j<8;j++) bf[j] = (short)f2bf(ldf(xin, (long long)srcs[j]*CIN + cin, xisf));
      }
      acc[ct] = mfma16x16x32(af, bf, acc[ct]);
    }
  }

  int dg = re - rs;
  float inv = 1.f / (float)(dg > 0 ? dg : 1);
  u16* row = ab + (size_t)(t - c0)*KPAD;
  #pragma unroll
  for (int ct=0; ct<NT; ct++){
    int cin = ct*16 + m;
    if (cin < CIN){
      #pragma unroll
      for (int r=0;r<4;r++){
        int k = q*4 + r;
        if (k < KG) row[cin*KG + k] = f2bf(acc[ct][r]*inv);
      }
    }
  }
  // append raw x (root term) + zero pad up to KPAD
  for (int idx = lane; idx < KPAD - KC; idx += 64){
    u16 v = 0;
    if (idx < CIN) v = f2bf(ldf(xin, (long long)t*CIN + idx, xisf));
    row[KC + idx] = v;
  }
}

// ---------------- B repack: [G ; root ; 0] into MFMA-fragment order ----------------
__global__ __launch_bounds__(256) void k_repack(const void* g, const void* root,
                                                u16* __restrict__ bp, int KC, int CIN, int COUT,
                                                int KS, int NCT, const int* flags){
  int tid = blockIdx.x*256 + threadIdx.x;
  int total = NCT*KS*64;
  if (tid >= total) return;
  int isf = flags[0];
  int lane = tid & 63;
  int ks = (tid >> 6) % KS;
  int ct = tid / (64*KS);
  int c = ct*16 + (lane & 15);
  int kbase = ks*32 + (lane >> 4)*8;
  short8 v8 = {};
  #pragma unroll
  for (int j=0;j<8;j++){
    int kk = kbase + j; u16 v = 0;
    if (c < COUT){
      if (kk < KC)            v = f2bf(ldf(g, (long long)kk*COUT + c, isf));
      else if (kk < KC + CIN) v = f2bf(ldf(root, (long long)(kk-KC)*COUT + c, isf));
    }
    v8[j] = (short)v;
  }
  ((short8*)bp)[tid] = v8;
}

// ---------------- Phase B (MFMA): [nrows, KPAD] @ [KPAD, COUT] + bias (+ELU) ----------------
template<int KPAD, int COUT, int NCT, bool FINAL>
__global__ __launch_bounds__(256) void k_phaseB(
    const u16* __restrict__ ab, const u16* __restrict__ bp, const void* bias,
    u16* __restrict__ h, float* __restrict__ outp, int c0, int nrows, const int* flags)
{
  constexpr int KS = KPAD/32;
  int isf = flags[0];
  int wv = threadIdx.x >> 6, lane = threadIdx.x & 63;
  int rt = blockIdx.x*4 + wv;
  if (rt*16 >= nrows) return;
  int m = lane & 15, q = lane >> 4;
  int lr = rt*16 + m;
  const short8* bpv = (const short8*)bp;
  f32x4 acc[NCT] = {};
  for (int ks=0; ks<KS; ks++){
    short8 af = *(const short8*)(ab + (size_t)lr*KPAD + ks*32 + q*8);
    #pragma unroll
    for (int ct=0; ct<NCT; ct++){
      short8 bf = bpv[(ct*KS + ks)*64 + lane];
      acc[ct] = mfma16x16x32(af, bf, acc[ct]);
    }
  }
  int row0 = c0 + rt*16;
  #pragma unroll
  for (int ct=0; ct<NCT; ct++){
    int col = ct*16 + m;
    if (col < COUT){
      float bv = ldf(bias, col, isf);
      #pragma unroll
      for (int r=0;r<4;r++){
        int rrow = row0 + q*4 + r;
        if (rrow < c0 + nrows){
          float v = acc[ct][r] + bv;
          if (!FINAL){
            v = (v > 0.f) ? v : (__expf(v) - 1.f);   // ELU
            h[(size_t)rrow*COUT + col] = f2bf(v);
          } else {
            outp[(size_t)rrow*COUT + col] = v;       // f32 output
          }
        }
      }
    }
  }
}

// ---------------- BN stats + apply ----------------
__global__ __launch_bounds__(256) void k_stats(const u16* __restrict__ h, float* __restrict__ sums,
                                               float* __restrict__ sumsq, int COUT){
  __shared__ float sS[256], sQ[256];
  int t = threadIdx.x;
  int c = t & 127, rg = t >> 7;
  float s = 0.f, qq = 0.f;
  int r0 = blockIdx.x*512 + rg*256;
  if (c < COUT){
    for (int i=0;i<256;i++){
      int r = r0 + i;
      if (r < NN){ float v = bf2f(h[(size_t)r*COUT + c]); s += v; qq += v*v; }
    }
  }
  sS[t] = s; sQ[t] = qq; __syncthreads();
  if (t < 128){
    float a = sS[t] + sS[t+128];
    float b = sQ[t] + sQ[t+128];
    if (t < COUT){ atomicAdd(&sums[t], a); atomicAdd(&sumsq[t], b); }
  }
}

__global__ __launch_bounds__(256) void k_bn(const u16* __restrict__ h, const void* gamma,
                                            const void* beta, const float* __restrict__ sums,
                                            const float* __restrict__ sumsq, u16* __restrict__ xo,
                                            int COUT, const int* flags){
  int t = threadIdx.x;
  int isf = flags[0];
  int c = t & 127;
  int r = blockIdx.x*2 + (t >> 7);
  if (c >= COUT || r >= NN) return;
  const float invn = 1.f/(float)NN;
  float mean = sums[c]*invn;
  float var  = sumsq[c]*invn - mean*mean;
  float g = ldf(gamma, c, isf), b = ldf(beta, c, isf);
  float v = g*(bf2f(h[(size_t)r*COUT + c]) - mean)*rsqrtf(var + 1e-5f) + b;
  xo[(size_t)r*COUT + c] = f2bf(v);
}

// ---------------- host ----------------
extern "C" void kernel_launch(void* const* d_in, const int* in_sizes, int n_in,
                              void* d_out, int out_size, void* d_ws, size_t ws_size,
                              hipStream_t stream)
{
  // ---- input mapping self-check (validated round 4) ----
  static const int expected[29] = {
    5000000, 3200000, 4800000,
    56250, 45, 45, 3750, 75, 75, 75,
    112500, 45, 45, 7500, 100, 100, 100,
    112500, 45, 45, 7500, 75, 75, 75,
    56250, 45, 45, 3750, 50
  };
  if (n_in != 29){ k_sentinel<<<1, 64, 0, stream>>>((float*)d_out, 512.0f); return; }
  for (int j=0;j<29;j++){
    if (in_sizes[j] != expected[j]){
      k_sentinel<<<1, 64, 0, stream>>>((float*)d_out, 1024.0f*(float)(1+j));
      return;
    }
  }

  const void* x0   = d_in[0];
  const void* ei   = d_in[1];
  const void* attr = d_in[2];
  const void* G[4]  = {d_in[3],  d_in[10], d_in[17], d_in[24]};
  const void* MU[4] = {d_in[4],  d_in[11], d_in[18], d_in[25]};
  const void* SG[4] = {d_in[5],  d_in[12], d_in[19], d_in[26]};
  const void* RT[4] = {d_in[6],  d_in[13], d_in[20], d_in[27]};
  const void* BI[4] = {d_in[7],  d_in[14], d_in[21], d_in[28]};
  const void* GA[3] = {d_in[8],  d_in[15], d_in[22]};
  const void* BE[3] = {d_in[9],  d_in[16], d_in[23]};

  char* w = (char*)d_ws;
  auto alloc = [&](size_t bytes)->char*{ char* p = w; w += (bytes + 255) & ~(size_t)255; return p; };
  int*  flags = (int*) alloc(256);
  int*  deg  = (int*) alloc((size_t)NN*4);
  int*  cur  = (int*) alloc((size_t)NN*4);
  int*  rp   = (int*) alloc((size_t)(NN+1)*4);
  int*  bsum = (int*) alloc(512*4);
  int*  perm = (int*) alloc((size_t)NE*4);             // 6.4 MB
  u16*  h    = (u16*) alloc((size_t)NN*100*2);         // 20 MB
  u16*  xb   = (u16*) alloc((size_t)NN*100*2);         // 20 MB
  u16*  bp   = (u16*) alloc(1<<19);                    // 512 KB
  float* sums  = (float*)alloc(512);
  float* sumsq = (float*)alloc(512);

  // ---- runtime-adaptive chunk: ab gets the remaining workspace ----
  size_t used = (size_t)(w - (char*)d_ws);
  size_t rem = (ws_size > used + 256) ? (ws_size - used - 256) : 0;
  int chunk = (int)(rem / (1600*2));
  chunk = (chunk / 2000) * 2000;
  if (chunk > 12000) chunk = 12000;
  if (chunk < 2000){
    float mb = (float)(ws_size >> 20); if (mb > 255.f) mb = 255.f;
    k_sentinel<<<1, 64, 0, stream>>>((float*)d_out, 65536.0f + 256.0f*mb);
    return;
  }
  u16* ab = (u16*)alloc((size_t)chunk*1600*2);

  k_probe<<<1, 64, 0, stream>>>(SG[0], ei, flags);

  hipMemsetAsync(deg, 0, (size_t)NN*4, stream);
  hipMemsetAsync(cur, 0, (size_t)NN*4, stream);
  k_deg  <<<NE/256, 256, 0, stream>>>(ei, deg, flags);
  k_scan1<<<(NN+1023)/1024, 256, 0, stream>>>(deg, rp, bsum);
  k_scan2<<<1, 128, 0, stream>>>(bsum, rp);
  k_scan3<<<(NN+1023)/1024, 256, 0, stream>>>(rp, bsum);
  k_fillp<<<NE/256, 256, 0, stream>>>(ei, rp, cur, perm, flags);

  auto layer = [&](auto phaseA, auto phaseB, const void* xin, int xmode,
                   int li, int KC, int CIN, int COUT, int KS, int NCT){
    k_repack<<<(NCT*KS*64 + 255)/256, 256, 0, stream>>>(G[li], RT[li], bp, KC, CIN, COUT, KS, NCT, flags);
    for (int c0 = 0; c0 < NN; c0 += chunk){
      int nrows = (NN - c0 < chunk) ? (NN - c0) : chunk;
      int gridA = (nrows + 3)/4;
      int gridB = ((nrows + 15)/16 + 3)/4;
      phaseA(gridA, xin, xmode, li, c0, nrows);
      phaseB(gridB, li, c0, nrows);
    }
  };

  // ---- layer 1: 50 -> 75
  layer([&](int gA, const void* xi, int xm, int li, int c0, int nr){
          k_phaseA<50><<<gA, 256, 0, stream>>>(perm, rp, ei, attr, xi, xm, MU[li], SG[li], ab, c0, nr, flags); },
        [&](int gB, int li, int c0, int nr){
          k_phaseB<800,75,5,false><<<gB, 256, 0, stream>>>(ab, bp, BI[li], h, nullptr, c0, nr, flags); },
        x0, 1, 0, 750, 50, 75, 25, 5);
  hipMemsetAsync(sums, 0, 512, stream); hipMemsetAsync(sumsq, 0, 512, stream);
  k_stats<<<(NN+511)/512, 256, 0, stream>>>(h, sums, sumsq, 75);
  k_bn<<<NN/2, 256, 0, stream>>>(h, GA[0], BE[0], sums, sumsq, xb, 75, flags);

  // ---- layer 2: 75 -> 100
  layer([&](int gA, const void* xi, int xm, int li, int c0, int nr){
          k_phaseA<75><<<gA, 256, 0, stream>>>(perm, rp, ei, attr, xi, xm, MU[li], SG[li], ab, c0, nr, flags); },
        [&](int gB, int li, int c0, int nr){
          k_phaseB<1216,100,7,false><<<gB, 256, 0, stream>>>(ab, bp, BI[li], h, nullptr, c0, nr, flags); },
        xb, 0, 1, 1125, 75, 100, 38, 7);
  hipMemsetAsync(sums, 0, 512, stream); hipMemsetAsync(sumsq, 0, 512, stream);
  k_stats<<<(NN+511)/512, 256, 0, stream>>>(h, sums, sumsq, 100);
  k_bn<<<NN/2, 256, 0, stream>>>(h, GA[1], BE[1], sums, sumsq, xb, 100, flags);

  // ---- layer 3: 100 -> 75
  layer([&](int gA, const void* xi, int xm, int li, int c0, int nr){
          k_phaseA<100><<<gA, 256, 0, stream>>>(perm, rp, ei, attr, xi, xm, MU[li], SG[li], ab, c0, nr, flags); },
        [&](int gB, int li, int c0, int nr){
          k_phaseB<1600,75,5,false><<<gB, 256, 0, stream>>>(ab, bp, BI[li], h, nullptr, c0, nr, flags); },
        xb, 0, 2, 1500, 100, 75, 50, 5);
  hipMemsetAsync(sums, 0, 512, stream); hipMemsetAsync(sumsq, 0, 512, stream);
  k_stats<<<(NN+511)/512, 256, 0, stream>>>(h, sums, sumsq, 75);
  k_bn<<<NN/2, 256, 0, stream>>>(h, GA[2], BE[2], sums, sumsq, xb, 75, flags);

  // ---- layer 4: 75 -> 50 (no ELU, no BN, f32 out)
  layer([&](int gA, const void* xi, int xm, int li, int c0, int nr){
          k_phaseA<75><<<gA, 256, 0, stream>>>(perm, rp, ei, attr, xi, xm, MU[li], SG[li], ab, c0, nr, flags); },
        [&](int gB, int li, int c0, int nr){
          k_phaseB<1216,50,4,true><<<gB, 256, 0, stream>>>(ab, bp, BI[li], nullptr, (float*)d_out, c0, nr, flags); },
        xb, 0, 3, 1125, 75, 50, 38, 4);
}